// Round 19
// baseline (657.162 us; speedup 1.0000x reference)
//
#include <hip/hip_runtime.h>

#define NSTEP 10

typedef __attribute__((ext_vector_type(8))) short bf16x8;   // 8 bf16 = 4 VGPRs
typedef __attribute__((ext_vector_type(4))) float f32x4;    // MFMA C/D

// ---------------------------------------------------------------------------
// Prep 1: transpose W1 [256][250] -> W1T [250][256]
// ---------------------------------------------------------------------------
extern "C" __global__ void __launch_bounds__(256) snn_prep(
    const float* __restrict__ W1, float* __restrict__ W1T)
{
    int i0 = blockIdx.x * 256 + threadIdx.x;
    int stride = gridDim.x * 256;
    for (int idx = i0; idx < 250 * 256; idx += stride) {
        int k = idx >> 8;
        int n = idx & 255;
        W1T[idx] = W1[n * 250 + k];
    }
}

// ---------------------------------------------------------------------------
// Prep 2: exact 3-way bf16 split of W2 into MFMA B-fragment layout
// (identical to R5..R18). [strip 0..7][split 0..2][slab 0..7][lane][8]
// ---------------------------------------------------------------------------
__device__ __forceinline__ unsigned int bf16_rne_hi(float f) {
    unsigned int u = __float_as_uint(f);
    return (u + 0x7FFFu + ((u >> 16) & 1u)) & 0xFFFF0000u;
}

extern "C" __global__ void __launch_bounds__(256) snn_prep2(
    const float* __restrict__ W2, unsigned short* __restrict__ W2F)
{
    int idx = blockIdx.x * 256 + threadIdx.x;   // 8*3*8*64 = 12288 items
    if (idx >= 8 * 3 * 8 * 64) return;
    int lane  = idx & 63;
    int slab  = (idx >> 6) & 7;
    int split = (idx >> 9) % 3;
    int w     = idx / (3 * 8 * 64);
    int j  = w * 16 + (lane & 15);
    int k0 = slab * 32 + (lane >> 4) * 8;
    unsigned short res[8];
    #pragma unroll
    for (int e = 0; e < 8; ++e) {
        float wval = W2[j * 256 + k0 + e];
        unsigned int u1 = bf16_rne_hi(wval);
        float r1 = __fsub_rn(wval, __uint_as_float(u1));
        unsigned int u2 = bf16_rne_hi(r1);
        float r2 = __fsub_rn(r1, __uint_as_float(u2));
        unsigned int u3 = bf16_rne_hi(r2);
        unsigned int sel = (split == 0) ? u1 : (split == 1) ? u2 : u3;
        res[e] = (unsigned short)(sel >> 16);
    }
    *(uint4*)&W2F[(((w * 3 + split) * 8 + slab) << 9) + lane * 8] =
        *(uint4*)res;
}

// ---------------------------------------------------------------------------
// snn_cur1 (R19): 4 samples/thread (64 samples/block, 2048 blocks). The same
// 16 w-values per k now feed 64 FMAs (was 32) and the x read widens to b128
// -> FMA issue fraction 53% -> 68%. Every (n,s) fmaf chain remains k-ascending
// + bias-after-dot => bit-identical curG regardless of blocking (R14/R15/R16
// precedent, 3/3 pass).
// Thread map: nt=t&15 -> neurons n = 64j + 4nt + e (j,e = 0..3);
//             st=t>>4 (0..15) -> samples s0a = st*4 .. +3.
// LDS: W1c f32[25][256] (25600 B) + xc f32[2][25][68] (13600 B) = 39200 B
// -> 4 blocks/CU. No launch-bounds caps (R9 law).
// ---------------------------------------------------------------------------
extern "C" __global__ void __launch_bounds__(256) snn_cur1(
    const float* __restrict__ x,
    const float* __restrict__ b1,
    const float* __restrict__ W1T,
    float* __restrict__ curG)
{
    __shared__ __align__(16) float W1c[25 * 256];    // 25600 B
    __shared__ __align__(16) float xc[2][25 * 68];   // 13600 B
    const int t   = threadIdx.x;
    const int nt  = t & 15;
    const int st  = t >> 4;          // 0..15
    const int s0a = st * 4;
    const int nt4 = nt * 4;
    const int sBase = blockIdx.x * 64;

    // prologue: stage x chunk 0 directly; prefetch W1T chunk 0 into regs
    for (int i = t; i < 1600; i += 256) {
        int sl = i / 25;
        int e  = i - sl * 25;
        xc[0][e * 68 + sl] = x[(size_t)(sBase + sl) * 250 + e];
    }
    float rs[25];
    #pragma unroll
    for (int j = 0; j < 25; ++j) rs[j] = W1T[j * 256 + t];
    float xs[7];
    #pragma unroll
    for (int r = 0; r < 7; ++r) xs[r] = 0.0f;

    float cur1[4][4][4];   // [j][e][s], neuron n = 64j + 4nt + e, sample s0a+s
    #pragma unroll
    for (int j = 0; j < 4; ++j)
        #pragma unroll
        for (int e = 0; e < 4; ++e)
            #pragma unroll
            for (int s = 0; s < 4; ++s) cur1[j][e][s] = 0.0f;

    __syncthreads();   // xc[0] staged

    for (int c = 0; c < 10; ++c) {
        // write W1c for chunk c (regs staged last iteration / prologue)
        #pragma unroll
        for (int j = 0; j < 25; ++j) W1c[j * 256 + t] = rs[j];
        // write x chunk c into xc[c&1] (chunk 0 staged in prologue)
        if (c > 0) {
            #pragma unroll
            for (int r = 0; r < 7; ++r) {
                int i = t + 256 * r;
                if (i < 1600) {
                    int sl = i / 25;
                    int e  = i - sl * 25;
                    xc[c & 1][e * 68 + sl] = xs[r];
                }
            }
        }
        // issue next chunk's global loads (hide under compute)
        if (c < 9) {
            const float* srcW = W1T + (c + 1) * 6400;
            #pragma unroll
            for (int j = 0; j < 25; ++j) rs[j] = srcW[j * 256 + t];
            #pragma unroll
            for (int r = 0; r < 7; ++r) {
                int i = t + 256 * r;
                if (i < 1600) {
                    int sl = i / 25;
                    int e  = i - sl * 25;
                    xs[r] = x[(size_t)(sBase + sl) * 250 + (c + 1) * 25 + e];
                }
            }
        }
        __syncthreads();   // W1c(c) + xc[c&1] ready

        const float* xrow = &xc[c & 1][0];
        #pragma unroll 5
        for (int kl = 0; kl < 25; ++kl) {
            const float4 xp = *(const float4*)&xrow[kl * 68 + s0a];
            const float* xv = &xp.x;
            float w[16];
            *(float4*)&w[0]  = *(const float4*)&W1c[kl * 256 +   0 + nt4];
            *(float4*)&w[4]  = *(const float4*)&W1c[kl * 256 +  64 + nt4];
            *(float4*)&w[8]  = *(const float4*)&W1c[kl * 256 + 128 + nt4];
            *(float4*)&w[12] = *(const float4*)&W1c[kl * 256 + 192 + nt4];
            #pragma unroll
            for (int j = 0; j < 4; ++j)
                #pragma unroll
                for (int e = 0; e < 4; ++e)
                    #pragma unroll
                    for (int s = 0; s < 4; ++s)
                        cur1[j][e][s] = fmaf(w[j * 4 + e], xv[s], cur1[j][e][s]);
        }
        if (c < 9) __syncthreads();   // readers done before next overwrite
    }

    {   // bias after dot (same per-chain order as R16/R18)
        float bb[16];
        #pragma unroll
        for (int j = 0; j < 4; ++j)
            *(float4*)&bb[j * 4] = *(const float4*)&b1[j * 64 + nt4];
        #pragma unroll
        for (int j = 0; j < 4; ++j)
            #pragma unroll
            for (int e = 0; e < 4; ++e)
                #pragma unroll
                for (int s = 0; s < 4; ++s)
                    cur1[j][e][s] = __fadd_rn(cur1[j][e][s], bb[j * 4 + e]);
    }
    #pragma unroll
    for (int s = 0; s < 4; ++s)
        #pragma unroll
        for (int j = 0; j < 4; ++j) {
            *(float4*)&curG[(size_t)(sBase + s0a + s) * 256 + j * 64 + nt4] =
                make_float4(cur1[j][0][s], cur1[j][1][s],
                            cur1[j][2][s], cur1[j][3][s]);
        }
}

// ---------------------------------------------------------------------------
// snn_main_split: EXACT R16/R18 version (measured 390 us, absmax 0.0).
// cur1 in LDS (thread-private, swizzled), 2-deep B-fragment prefetch.
// LDS: cur1L [0,65536) | s1bf [65536,98304) | s2Lb [98304,107520)
//      W3L [107520,111616) | pL [111616,116736) | bL [116736,117268)
// ---------------------------------------------------------------------------
extern "C" __global__ void __launch_bounds__(512, 2) snn_main_split(
    const float* __restrict__ curG,
    const float* __restrict__ b2g,
    const float* __restrict__ W3,
    const float* __restrict__ b3,
    const unsigned short* __restrict__ W2F,
    float* __restrict__ out)
{
    __shared__ __align__(16) char ldsraw[117280];
    float* cur1L = (float*)(ldsraw);                          // [512][32] f32
    char* s1bf = ldsraw + 65536;                              // [64][512B]
    unsigned char* s2Lb = (unsigned char*)(ldsraw + 98304);   // [128][72]
    float* W3L = (float*)(ldsraw + 107520);                   // [128][8]
    float* pL  = (float*)(ldsraw + 111616);                   // [20][64]
    float* bL  = (float*)(ldsraw + 116736);                   // [133]

    const int t    = threadIdx.x;
    const int nt   = t & 15;
    const int st   = t >> 4;          // 0..31
    const int s0a  = st * 2;
    const int n0   = nt * 16;
    const int lane = t & 63;
    const int wv   = t >> 6;          // 0..7 (j-strip)
    const int l15  = lane & 15;
    const int lq   = lane >> 4;       // 0..3
    const int sBase = blockIdx.x * 64;
    const int tk   = t & 7;           // cur1L chunk swizzle key
    float* myc = cur1L + t * 32;

    // ---- prologue: load cur1 from curG, park it in LDS (thread-private) ----
    #pragma unroll
    for (int s = 0; s < 2; ++s) {
        const float4* cp =
            (const float4*)&curG[(size_t)(sBase + s0a + s) * 256 + n0];
        #pragma unroll
        for (int q = 0; q < 4; ++q) {
            float4 v = cp[q];
            *(float4*)&myc[((s * 4 + q) ^ tk) * 4] = v;
        }
    }

    // ---- stage W3 (transposed, padded to 8) + biases ----
    for (int idx = t; idx < 640; idx += 512) {
        int o = idx >> 7;             // W3 is [5][128]
        int j = idx & 127;
        W3L[j * 8 + o] = W3[idx];
    }
    if (t < 128) bL[t] = b2g[t];
    if (t < 5)   bL[128 + t] = b3[t];
    __syncthreads();   // W3L/bL staged

    // ---- persistent state ----
    float m1[16][2];
    #pragma unroll
    for (int i = 0; i < 16; ++i) { m1[i][0] = 0.0f; m1[i][1] = 0.0f; }
    float m2[4][4];
    #pragma unroll
    for (int mt = 0; mt < 4; ++mt)
        #pragma unroll
        for (int rg = 0; rg < 4; ++rg) m2[mt][rg] = 0.0f;
    float m3 = 0.0f, acc3 = 0.0f;

    const unsigned short* fb = W2F + (wv * 24) * 512 + lane * 8;
    const int keyB   = (lane & 7) << 4;
    const int chunkq = lq << 4;
    const int jC     = wv * 16 + l15;
    const int keyC2  = ((jC >> 2) & 7) << 3;

    #pragma unroll 1
    for (int stp = 0; stp < NSTEP; ++stp) {
        // ========== A: layer-1 LIF + bf16 spikes -> LDS ==========
        {
            float c1v[16][2];
            #pragma unroll
            for (int s = 0; s < 2; ++s)
                #pragma unroll
                for (int q = 0; q < 4; ++q) {
                    float4 v = *(const float4*)&myc[((s * 4 + q) ^ tk) * 4];
                    c1v[q * 4 + 0][s] = v.x;
                    c1v[q * 4 + 1][s] = v.y;
                    c1v[q * 4 + 2][s] = v.z;
                    c1v[q * 4 + 3][s] = v.w;
                }
            unsigned int dwa[2][8];
            #pragma unroll
            for (int i = 0; i < 16; ++i) {
                #pragma unroll
                for (int s = 0; s < 2; ++s) {
                    float m = m1[i][s];
                    float r = (m > 1.0f) ? 1.0f : 0.0f;
                    m = __fsub_rn(__fadd_rn(__fmul_rn(0.9f, m), c1v[i][s]), r);
                    m1[i][s] = m;
                    unsigned int bits = (m > 1.0f) ? 0x3F80u : 0u;
                    if (i & 1) dwa[s][i >> 1] |= bits << 16;
                    else       dwa[s][i >> 1]  = bits;
                }
            }
            #pragma unroll
            for (int s = 0; s < 2; ++s) {
                const int row = s0a + s;
                const int key = row & 7;
                char* rp = s1bf + row * 512;
                uint4 lo = make_uint4(dwa[s][0], dwa[s][1], dwa[s][2], dwa[s][3]);
                uint4 hi = make_uint4(dwa[s][4], dwa[s][5], dwa[s][6], dwa[s][7]);
                *(uint4*)(rp + (((2 * nt + 0) ^ key) << 4)) = lo;
                *(uint4*)(rp + (((2 * nt + 1) ^ key) << 4)) = hi;
            }
        }
        __syncthreads();   // bar1: s1 ready

        // ========== B: cur2 = s1 @ W2.T via MFMA (2-deep B prefetch) ========
        f32x4 acc[4];
        {
            const f32x4 z = {0.0f, 0.0f, 0.0f, 0.0f};
            acc[0] = z; acc[1] = z; acc[2] = z; acc[3] = z;
        }
        bf16x8 B2c = *(const bf16x8*)(fb + (16 + 0) * 512);
        bf16x8 B1c = *(const bf16x8*)(fb + (8  + 0) * 512);
        bf16x8 B0c = *(const bf16x8*)(fb + (0  + 0) * 512);
        bf16x8 B2n = *(const bf16x8*)(fb + (16 + 1) * 512);
        bf16x8 B1n = *(const bf16x8*)(fb + (8  + 1) * 512);
        bf16x8 B0n = *(const bf16x8*)(fb + (0  + 1) * 512);
        #pragma unroll
        for (int slab = 0; slab < 8; ++slab) {
            bf16x8 B2f, B1f, B0f;
            if (slab < 6) {
                B2f = *(const bf16x8*)(fb + (16 + slab + 2) * 512);
                B1f = *(const bf16x8*)(fb + (8  + slab + 2) * 512);
                B0f = *(const bf16x8*)(fb + (0  + slab + 2) * 512);
            }
            const int coff = (slab * 64 + chunkq) ^ keyB;
            const bf16x8 A0 = *(const bf16x8*)(s1bf + (l15     ) * 512 + coff);
            const bf16x8 A1 = *(const bf16x8*)(s1bf + (l15 + 16) * 512 + coff);
            const bf16x8 A2 = *(const bf16x8*)(s1bf + (l15 + 32) * 512 + coff);
            const bf16x8 A3 = *(const bf16x8*)(s1bf + (l15 + 48) * 512 + coff);
            acc[0] = __builtin_amdgcn_mfma_f32_16x16x32_bf16(A0, B2c, acc[0], 0, 0, 0);
            acc[1] = __builtin_amdgcn_mfma_f32_16x16x32_bf16(A1, B2c, acc[1], 0, 0, 0);
            acc[2] = __builtin_amdgcn_mfma_f32_16x16x32_bf16(A2, B2c, acc[2], 0, 0, 0);
            acc[3] = __builtin_amdgcn_mfma_f32_16x16x32_bf16(A3, B2c, acc[3], 0, 0, 0);
            acc[0] = __builtin_amdgcn_mfma_f32_16x16x32_bf16(A0, B1c, acc[0], 0, 0, 0);
            acc[1] = __builtin_amdgcn_mfma_f32_16x16x32_bf16(A1, B1c, acc[1], 0, 0, 0);
            acc[2] = __builtin_amdgcn_mfma_f32_16x16x32_bf16(A2, B1c, acc[2], 0, 0, 0);
            acc[3] = __builtin_amdgcn_mfma_f32_16x16x32_bf16(A3, B1c, acc[3], 0, 0, 0);
            acc[0] = __builtin_amdgcn_mfma_f32_16x16x32_bf16(A0, B0c, acc[0], 0, 0, 0);
            acc[1] = __builtin_amdgcn_mfma_f32_16x16x32_bf16(A1, B0c, acc[1], 0, 0, 0);
            acc[2] = __builtin_amdgcn_mfma_f32_16x16x32_bf16(A2, B0c, acc[2], 0, 0, 0);
            acc[3] = __builtin_amdgcn_mfma_f32_16x16x32_bf16(A3, B0c, acc[3], 0, 0, 0);
            if (slab < 7) { B2c = B2n; B1c = B1n; B0c = B0n; }
            if (slab < 6) { B2n = B2f; B1n = B1f; B0n = B0f; }
        }

        // ========== C: layer-2 LIF + u8 spikes -> LDS ==========
        {
            const float bj = bL[jC];
            #pragma unroll
            for (int mt = 0; mt < 4; ++mt) {
                unsigned int pk = 0;
                #pragma unroll
                for (int rg = 0; rg < 4; ++rg) {
                    float c2 = __fadd_rn(acc[mt][rg], bj);
                    float m = m2[mt][rg];
                    float r = (m > 1.0f) ? 1.0f : 0.0f;
                    m = __fsub_rn(__fadd_rn(__fmul_rn(0.9f, m), c2), r);
                    m2[mt][rg] = m;
                    if (m > 1.0f) pk |= 1u << (8 * rg);
                }
                const int smp0 = mt * 16 + lq * 4;
                *(unsigned int*)&s2Lb[jC * 72 + (smp0 ^ keyC2)] = pk;
            }
        }
        __syncthreads();   // bar2: s2 ready

        // ========== D: layer-3 partial dots ==========
        if (t < 256) {
            const int sl = t & 63;
            const int jr = t >> 6;
            float part[5] = {0.0f, 0.0f, 0.0f, 0.0f, 0.0f};
            #pragma unroll 8
            for (int jj = 0; jj < 32; ++jj) {
                const int j = jr * 32 + jj;
                const float s2v =
                    (float)s2Lb[j * 72 + (sl ^ (((j >> 2) & 7) << 3))];
                const float4 w3a = *(const float4*)&W3L[j * 8];
                const float  w3e = W3L[j * 8 + 4];
                part[0] = fmaf(w3a.x, s2v, part[0]);
                part[1] = fmaf(w3a.y, s2v, part[1]);
                part[2] = fmaf(w3a.z, s2v, part[2]);
                part[3] = fmaf(w3a.w, s2v, part[3]);
                part[4] = fmaf(w3e,   s2v, part[4]);
            }
            #pragma unroll
            for (int o = 0; o < 5; ++o)
                pL[(o * 4 + jr) * 64 + sl] = part[o];
        }
        __syncthreads();   // bar3: partials ready

        // ========== E: layer-3 LIF + spike count ==========
        if (t < 320) {
            const int o  = t >> 6;
            const int sl = t & 63;
            float c3 = pL[(o * 4 + 0) * 64 + sl];
            c3 += pL[(o * 4 + 1) * 64 + sl];
            c3 += pL[(o * 4 + 2) * 64 + sl];
            c3 += pL[(o * 4 + 3) * 64 + sl];
            c3 = __fadd_rn(c3, bL[128 + o]);
            float m = m3;
            float r = (m > 1.0f) ? 1.0f : 0.0f;
            m = __fsub_rn(__fadd_rn(__fmul_rn(0.9f, m), c3), r);
            m3 = m;
            if (m > 1.0f) acc3 += 1.0f;
        }
    }

    if (t < 320) {
        out[(sBase + (t & 63)) * 5 + (t >> 6)] = acc3;
    }
}

// ---------------------------------------------------------------------------
// snn_main_fused: EXACT R10 kernel — fallback when ws_size cannot hold cur1G.
// ---------------------------------------------------------------------------
extern "C" __global__ void __launch_bounds__(512, 2) snn_main_fused(
    const float* __restrict__ x,
    const float* __restrict__ b1,
    const float* __restrict__ b2g,
    const float* __restrict__ W3,
    const float* __restrict__ b3,
    const float* __restrict__ W1T,
    const unsigned short* __restrict__ W2F,
    float* __restrict__ out)
{
    __shared__ __align__(16) char ldsraw[68000];
    char* s1bf = ldsraw;
    unsigned char* s2Lb = (unsigned char*)(ldsraw + 32768);
    float* W3L = (float*)(ldsraw + 41984);
    float* pL  = (float*)(ldsraw + 46080);
    float* bL  = (float*)(ldsraw + 51200);
    float* xT  = (float*)(ldsraw);

    const int t    = threadIdx.x;
    const int nt   = t & 15;
    const int st   = t >> 4;
    const int s0a  = st * 2;
    const int n0   = nt * 16;
    const int lane = t & 63;
    const int wv   = t >> 6;
    const int l15  = lane & 15;
    const int lq   = lane >> 4;
    const int sBase = blockIdx.x * 64;

    for (int i = t; i < 64 * 250; i += 512) {
        int sl = i / 250;
        int kl = i - sl * 250;
        xT[kl * 68 + sl] = x[(sBase + sl) * 250 + kl];
    }
    __syncthreads();

    float cur1[16][2];
    #pragma unroll
    for (int i = 0; i < 16; ++i) { cur1[i][0] = 0.0f; cur1[i][1] = 0.0f; }

    #pragma unroll 5
    for (int k = 0; k < 250; ++k) {
        const float2 xp = *(const float2*)&xT[k * 68 + s0a];
        const float x0 = xp.x;
        const float x1 = xp.y;
        float w[16];
        *(float4*)&w[0]  = *(const float4*)&W1T[k * 256 + n0];
        *(float4*)&w[4]  = *(const float4*)&W1T[k * 256 + n0 + 4];
        *(float4*)&w[8]  = *(const float4*)&W1T[k * 256 + n0 + 8];
        *(float4*)&w[12] = *(const float4*)&W1T[k * 256 + n0 + 12];
        #pragma unroll
        for (int i = 0; i < 16; ++i) {
            cur1[i][0] = fmaf(w[i], x0, cur1[i][0]);
            cur1[i][1] = fmaf(w[i], x1, cur1[i][1]);
        }
    }
    {
        float bb[16];
        *(float4*)&bb[0]  = *(const float4*)&b1[n0];
        *(float4*)&bb[4]  = *(const float4*)&b1[n0 + 4];
        *(float4*)&bb[8]  = *(const float4*)&b1[n0 + 8];
        *(float4*)&bb[12] = *(const float4*)&b1[n0 + 12];
        #pragma unroll
        for (int i = 0; i < 16; ++i) {
            cur1[i][0] = __fadd_rn(cur1[i][0], bb[i]);
            cur1[i][1] = __fadd_rn(cur1[i][1], bb[i]);
        }
    }
    __syncthreads();

    for (int idx = t; idx < 640; idx += 512) {
        int o = idx >> 7;
        int j = idx & 127;
        W3L[j * 8 + o] = W3[idx];
    }
    if (t < 128) bL[t] = b2g[t];
    if (t < 5)   bL[128 + t] = b3[t];
    __syncthreads();

    float m1[16][2];
    #pragma unroll
    for (int i = 0; i < 16; ++i) { m1[i][0] = 0.0f; m1[i][1] = 0.0f; }
    float m2[4][4];
    #pragma unroll
    for (int mt = 0; mt < 4; ++mt)
        #pragma unroll
        for (int rg = 0; rg < 4; ++rg) m2[mt][rg] = 0.0f;
    float m3 = 0.0f, acc3 = 0.0f;

    const unsigned short* fb = W2F + (wv * 24) * 512 + lane * 8;
    const int keyB   = (lane & 7) << 4;
    const int chunkq = lq << 4;
    const int jC     = wv * 16 + l15;
    const int keyC2  = ((jC >> 2) & 7) << 3;

    #pragma unroll 1
    for (int stp = 0; stp < NSTEP; ++stp) {
        {
            unsigned int dwa[2][8];
            #pragma unroll
            for (int i = 0; i < 16; ++i) {
                #pragma unroll
                for (int s = 0; s < 2; ++s) {
                    float m = m1[i][s];
                    float r = (m > 1.0f) ? 1.0f : 0.0f;
                    m = __fsub_rn(__fadd_rn(__fmul_rn(0.9f, m), cur1[i][s]), r);
                    m1[i][s] = m;
                    unsigned int bits = (m > 1.0f) ? 0x3F80u : 0u;
                    if (i & 1) dwa[s][i >> 1] |= bits << 16;
                    else       dwa[s][i >> 1]  = bits;
                }
            }
            #pragma unroll
            for (int s = 0; s < 2; ++s) {
                const int row = s0a + s;
                const int key = row & 7;
                char* rp = s1bf + row * 512;
                uint4 lo = make_uint4(dwa[s][0], dwa[s][1], dwa[s][2], dwa[s][3]);
                uint4 hi = make_uint4(dwa[s][4], dwa[s][5], dwa[s][6], dwa[s][7]);
                *(uint4*)(rp + (((2 * nt + 0) ^ key) << 4)) = lo;
                *(uint4*)(rp + (((2 * nt + 1) ^ key) << 4)) = hi;
            }
        }
        __syncthreads();

        f32x4 acc[4];
        {
            const f32x4 z = {0.0f, 0.0f, 0.0f, 0.0f};
            acc[0] = z; acc[1] = z; acc[2] = z; acc[3] = z;
        }
        #pragma unroll
        for (int slab = 0; slab < 8; ++slab) {
            const bf16x8 B2 = *(const bf16x8*)(fb + (16 + slab) * 512);
            const bf16x8 B1 = *(const bf16x8*)(fb + (8  + slab) * 512);
            const bf16x8 B0 = *(const bf16x8*)(fb + (0  + slab) * 512);
            const int coff = (slab * 64 + chunkq) ^ keyB;
            const bf16x8 A0 = *(const bf16x8*)(s1bf + (l15     ) * 512 + coff);
            const bf16x8 A1 = *(const bf16x8*)(s1bf + (l15 + 16) * 512 + coff);
            const bf16x8 A2 = *(const bf16x8*)(s1bf + (l15 + 32) * 512 + coff);
            const bf16x8 A3 = *(const bf16x8*)(s1bf + (l15 + 48) * 512 + coff);
            acc[0] = __builtin_amdgcn_mfma_f32_16x16x32_bf16(A0, B2, acc[0], 0, 0, 0);
            acc[1] = __builtin_amdgcn_mfma_f32_16x16x32_bf16(A1, B2, acc[1], 0, 0, 0);
            acc[2] = __builtin_amdgcn_mfma_f32_16x16x32_bf16(A2, B2, acc[2], 0, 0, 0);
            acc[3] = __builtin_amdgcn_mfma_f32_16x16x32_bf16(A3, B2, acc[3], 0, 0, 0);
            acc[0] = __builtin_amdgcn_mfma_f32_16x16x32_bf16(A0, B1, acc[0], 0, 0, 0);
            acc[1] = __builtin_amdgcn_mfma_f32_16x16x32_bf16(A1, B1, acc[1], 0, 0, 0);
            acc[2] = __builtin_amdgcn_mfma_f32_16x16x32_bf16(A2, B1, acc[2], 0, 0, 0);
            acc[3] = __builtin_amdgcn_mfma_f32_16x16x32_bf16(A3, B1, acc[3], 0, 0, 0);
            acc[0] = __builtin_amdgcn_mfma_f32_16x16x32_bf16(A0, B0, acc[0], 0, 0, 0);
            acc[1] = __builtin_amdgcn_mfma_f32_16x16x32_bf16(A1, B0, acc[1], 0, 0, 0);
            acc[2] = __builtin_amdgcn_mfma_f32_16x16x32_bf16(A2, B0, acc[2], 0, 0, 0);
            acc[3] = __builtin_amdgcn_mfma_f32_16x16x32_bf16(A3, B0, acc[3], 0, 0, 0);
        }

        {
            const float bj = bL[jC];
            #pragma unroll
            for (int mt = 0; mt < 4; ++mt) {
                unsigned int pk = 0;
                #pragma unroll
                for (int rg = 0; rg < 4; ++rg) {
                    float c2 = __fadd_rn(acc[mt][rg], bj);
                    float m = m2[mt][rg];
                    float r = (m > 1.0f) ? 1.0f : 0.0f;
                    m = __fsub_rn(__fadd_rn(__fmul_rn(0.9f, m), c2), r);
                    m2[mt][rg] = m;
                    if (m > 1.0f) pk |= 1u << (8 * rg);
                }
                const int smp0 = mt * 16 + lq * 4;
                *(unsigned int*)&s2Lb[jC * 72 + (smp0 ^ keyC2)] = pk;
            }
        }
        __syncthreads();

        if (t < 256) {
            const int sl = t & 63;
            const int jr = t >> 6;
            float part[5] = {0.0f, 0.0f, 0.0f, 0.0f, 0.0f};
            #pragma unroll 8
            for (int jj = 0; jj < 32; ++jj) {
                const int j = jr * 32 + jj;
                const float s2v =
                    (float)s2Lb[j * 72 + (sl ^ (((j >> 2) & 7) << 3))];
                const float4 w3a = *(const float4*)&W3L[j * 8];
                const float  w3e = W3L[j * 8 + 4];
                part[0] = fmaf(w3a.x, s2v, part[0]);
                part[1] = fmaf(w3a.y, s2v, part[1]);
                part[2] = fmaf(w3a.z, s2v, part[2]);
                part[3] = fmaf(w3a.w, s2v, part[3]);
                part[4] = fmaf(w3e,   s2v, part[4]);
            }
            #pragma unroll
            for (int o = 0; o < 5; ++o)
                pL[(o * 4 + jr) * 64 + sl] = part[o];
        }
        __syncthreads();

        if (t < 320) {
            const int o  = t >> 6;
            const int sl = t & 63;
            float c3 = pL[(o * 4 + 0) * 64 + sl];
            c3 += pL[(o * 4 + 1) * 64 + sl];
            c3 += pL[(o * 4 + 2) * 64 + sl];
            c3 += pL[(o * 4 + 3) * 64 + sl];
            c3 = __fadd_rn(c3, bL[128 + o]);
            float m = m3;
            float r = (m > 1.0f) ? 1.0f : 0.0f;
            m = __fsub_rn(__fadd_rn(__fmul_rn(0.9f, m), c3), r);
            m3 = m;
            if (m > 1.0f) acc3 += 1.0f;
        }
    }

    if (t < 320) {
        out[(sBase + (t & 63)) * 5 + (t >> 6)] = acc3;
    }
}

extern "C" void kernel_launch(void* const* d_in, const int* in_sizes, int n_in,
                              void* d_out, int out_size, void* d_ws, size_t ws_size,
                              hipStream_t stream) {
    const float* x  = (const float*)d_in[0];
    const float* W1 = (const float*)d_in[1];
    const float* b1 = (const float*)d_in[2];
    const float* W2 = (const float*)d_in[3];
    const float* b2 = (const float*)d_in[4];
    const float* W3 = (const float*)d_in[5];
    const float* b3 = (const float*)d_in[6];
    float* out = (float*)d_out;

    float* W1T = (float*)d_ws;                                     // 256000 B
    unsigned short* W2F = (unsigned short*)((char*)d_ws + 262144); // 196608 B

    const int B = in_sizes[0] / 250;      // 131072
    const size_t curBytes = (size_t)B * 256 * sizeof(float);       // 134.2 MB
    const size_t curOff   = 262144 + 196608;                       // 458752

    snn_prep <<<64, 256, 0, stream>>>(W1, W1T);
    snn_prep2<<<48, 256, 0, stream>>>(W2, W2F);

    if (ws_size >= curOff + curBytes) {
        float* curG = (float*)((char*)d_ws + curOff);
        snn_cur1<<<B / 64, 256, 0, stream>>>(x, b1, W1T, curG);
        snn_main_split<<<B / 64, 512, 0, stream>>>(curG, b2, W3, b3, W2F, out);
    } else {
        snn_main_fused<<<B / 64, 512, 0, stream>>>(x, b1, b2, W3, b3, W1T, W2F,
                                                   out);
    }
}

// Round 20
// 590.750 us; speedup vs baseline: 1.1124x; 1.1124x over previous
//
#include <hip/hip_runtime.h>

#define NSTEP 10

typedef __attribute__((ext_vector_type(8))) short bf16x8;   // 8 bf16 = 4 VGPRs
typedef __attribute__((ext_vector_type(4))) float f32x4;    // MFMA C/D

// ---------------------------------------------------------------------------
// Prep 1: transpose W1 [256][250] -> W1T [250][256]
// ---------------------------------------------------------------------------
extern "C" __global__ void __launch_bounds__(256) snn_prep(
    const float* __restrict__ W1, float* __restrict__ W1T)
{
    int i0 = blockIdx.x * 256 + threadIdx.x;
    int stride = gridDim.x * 256;
    for (int idx = i0; idx < 250 * 256; idx += stride) {
        int k = idx >> 8;
        int n = idx & 255;
        W1T[idx] = W1[n * 250 + k];
    }
}

// ---------------------------------------------------------------------------
// Prep 2: exact 3-way bf16 split of W2 into MFMA B-fragment layout
// (identical to R5..R18). [strip 0..7][split 0..2][slab 0..7][lane][8]
// ---------------------------------------------------------------------------
__device__ __forceinline__ unsigned int bf16_rne_hi(float f) {
    unsigned int u = __float_as_uint(f);
    return (u + 0x7FFFu + ((u >> 16) & 1u)) & 0xFFFF0000u;
}

extern "C" __global__ void __launch_bounds__(256) snn_prep2(
    const float* __restrict__ W2, unsigned short* __restrict__ W2F)
{
    int idx = blockIdx.x * 256 + threadIdx.x;   // 8*3*8*64 = 12288 items
    if (idx >= 8 * 3 * 8 * 64) return;
    int lane  = idx & 63;
    int slab  = (idx >> 6) & 7;
    int split = (idx >> 9) % 3;
    int w     = idx / (3 * 8 * 64);
    int j  = w * 16 + (lane & 15);
    int k0 = slab * 32 + (lane >> 4) * 8;
    unsigned short res[8];
    #pragma unroll
    for (int e = 0; e < 8; ++e) {
        float wval = W2[j * 256 + k0 + e];
        unsigned int u1 = bf16_rne_hi(wval);
        float r1 = __fsub_rn(wval, __uint_as_float(u1));
        unsigned int u2 = bf16_rne_hi(r1);
        float r2 = __fsub_rn(r1, __uint_as_float(u2));
        unsigned int u3 = bf16_rne_hi(r2);
        unsigned int sel = (split == 0) ? u1 : (split == 1) ? u2 : u3;
        res[e] = (unsigned short)(sel >> 16);
    }
    *(uint4*)&W2F[(((w * 3 + split) * 8 + slab) << 9) + lane * 8] =
        *(uint4*)res;
}

// ---------------------------------------------------------------------------
// snn_cur1: R16/R18 version verbatim (2 samples/thread, chunked x staging,
// 32.8 KB LDS -> 4 blocks/CU; measured ~185 us). R19's 4-sample variant
// regressed (+65 us): 64 accumulators pushed natural VGPR past the 128 tier.
// This config is the measured optimum between issue-bound and reg-bound.
// ---------------------------------------------------------------------------
extern "C" __global__ void __launch_bounds__(256) snn_cur1(
    const float* __restrict__ x,
    const float* __restrict__ b1,
    const float* __restrict__ W1T,
    float* __restrict__ curG)
{
    __shared__ __align__(16) float W1c[25 * 256];    // 25600 B
    __shared__ __align__(16) float xc[2][25 * 36];   // 7200 B
    const int t   = threadIdx.x;
    const int nt  = t & 15;
    const int st  = t >> 4;          // 0..15
    const int s0a = st * 2;
    const int nt4 = nt * 4;
    const int sBase = blockIdx.x * 32;

    for (int i = t; i < 800; i += 256) {
        int sl = i / 25;
        int e  = i - sl * 25;
        xc[0][e * 36 + sl] = x[(size_t)(sBase + sl) * 250 + e];
    }
    float rs[25];
    #pragma unroll
    for (int j = 0; j < 25; ++j) rs[j] = W1T[j * 256 + t];
    float xs[4] = {0.0f, 0.0f, 0.0f, 0.0f};

    float cur1[4][4][2];   // [j][e][s], neuron n = 64j + 4nt + e
    #pragma unroll
    for (int j = 0; j < 4; ++j)
        #pragma unroll
        for (int e = 0; e < 4; ++e) { cur1[j][e][0] = 0.0f; cur1[j][e][1] = 0.0f; }

    __syncthreads();   // xc[0] staged

    for (int c = 0; c < 10; ++c) {
        #pragma unroll
        for (int j = 0; j < 25; ++j) W1c[j * 256 + t] = rs[j];
        if (c > 0) {
            #pragma unroll
            for (int r = 0; r < 4; ++r) {
                int i = t + 256 * r;
                if (i < 800) {
                    int sl = i / 25;
                    int e  = i - sl * 25;
                    xc[c & 1][e * 36 + sl] = xs[r];
                }
            }
        }
        if (c < 9) {
            const float* srcW = W1T + (c + 1) * 6400;
            #pragma unroll
            for (int j = 0; j < 25; ++j) rs[j] = srcW[j * 256 + t];
            #pragma unroll
            for (int r = 0; r < 4; ++r) {
                int i = t + 256 * r;
                if (i < 800) {
                    int sl = i / 25;
                    int e  = i - sl * 25;
                    xs[r] = x[(size_t)(sBase + sl) * 250 + (c + 1) * 25 + e];
                }
            }
        }
        __syncthreads();   // W1c(c) + xc[c&1] ready

        const float* xrow = &xc[c & 1][0];
        #pragma unroll 5
        for (int kl = 0; kl < 25; ++kl) {
            const float2 xp = *(const float2*)&xrow[kl * 36 + s0a];
            float w[16];
            *(float4*)&w[0]  = *(const float4*)&W1c[kl * 256 +   0 + nt4];
            *(float4*)&w[4]  = *(const float4*)&W1c[kl * 256 +  64 + nt4];
            *(float4*)&w[8]  = *(const float4*)&W1c[kl * 256 + 128 + nt4];
            *(float4*)&w[12] = *(const float4*)&W1c[kl * 256 + 192 + nt4];
            #pragma unroll
            for (int j = 0; j < 4; ++j)
                #pragma unroll
                for (int e = 0; e < 4; ++e) {
                    cur1[j][e][0] = fmaf(w[j * 4 + e], xp.x, cur1[j][e][0]);
                    cur1[j][e][1] = fmaf(w[j * 4 + e], xp.y, cur1[j][e][1]);
                }
        }
        if (c < 9) __syncthreads();
    }

    {   // bias after dot
        float bb[16];
        #pragma unroll
        for (int j = 0; j < 4; ++j)
            *(float4*)&bb[j * 4] = *(const float4*)&b1[j * 64 + nt4];
        #pragma unroll
        for (int j = 0; j < 4; ++j)
            #pragma unroll
            for (int e = 0; e < 4; ++e) {
                cur1[j][e][0] = __fadd_rn(cur1[j][e][0], bb[j * 4 + e]);
                cur1[j][e][1] = __fadd_rn(cur1[j][e][1], bb[j * 4 + e]);
            }
    }
    #pragma unroll
    for (int s = 0; s < 2; ++s)
        #pragma unroll
        for (int j = 0; j < 4; ++j) {
            *(float4*)&curG[(size_t)(sBase + s0a + s) * 256 + j * 64 + nt4] =
                make_float4(cur1[j][0][s], cur1[j][1][s],
                            cur1[j][2][s], cur1[j][3][s]);
        }
}

// ---------------------------------------------------------------------------
// snn_main_split: EXACT R16/R18 version (measured 390 us, absmax 0.0).
// cur1 in LDS (thread-private, swizzled), 2-deep B-fragment prefetch.
// LDS: cur1L [0,65536) | s1bf [65536,98304) | s2Lb [98304,107520)
//      W3L [107520,111616) | pL [111616,116736) | bL [116736,117268)
// ---------------------------------------------------------------------------
extern "C" __global__ void __launch_bounds__(512, 2) snn_main_split(
    const float* __restrict__ curG,
    const float* __restrict__ b2g,
    const float* __restrict__ W3,
    const float* __restrict__ b3,
    const unsigned short* __restrict__ W2F,
    float* __restrict__ out)
{
    __shared__ __align__(16) char ldsraw[117280];
    float* cur1L = (float*)(ldsraw);                          // [512][32] f32
    char* s1bf = ldsraw + 65536;                              // [64][512B]
    unsigned char* s2Lb = (unsigned char*)(ldsraw + 98304);   // [128][72]
    float* W3L = (float*)(ldsraw + 107520);                   // [128][8]
    float* pL  = (float*)(ldsraw + 111616);                   // [20][64]
    float* bL  = (float*)(ldsraw + 116736);                   // [133]

    const int t    = threadIdx.x;
    const int nt   = t & 15;
    const int st   = t >> 4;          // 0..31
    const int s0a  = st * 2;
    const int n0   = nt * 16;
    const int lane = t & 63;
    const int wv   = t >> 6;          // 0..7 (j-strip)
    const int l15  = lane & 15;
    const int lq   = lane >> 4;       // 0..3
    const int sBase = blockIdx.x * 64;
    const int tk   = t & 7;           // cur1L chunk swizzle key
    float* myc = cur1L + t * 32;

    // ---- prologue: load cur1 from curG, park it in LDS (thread-private) ----
    #pragma unroll
    for (int s = 0; s < 2; ++s) {
        const float4* cp =
            (const float4*)&curG[(size_t)(sBase + s0a + s) * 256 + n0];
        #pragma unroll
        for (int q = 0; q < 4; ++q) {
            float4 v = cp[q];
            *(float4*)&myc[((s * 4 + q) ^ tk) * 4] = v;
        }
    }

    // ---- stage W3 (transposed, padded to 8) + biases ----
    for (int idx = t; idx < 640; idx += 512) {
        int o = idx >> 7;             // W3 is [5][128]
        int j = idx & 127;
        W3L[j * 8 + o] = W3[idx];
    }
    if (t < 128) bL[t] = b2g[t];
    if (t < 5)   bL[128 + t] = b3[t];
    __syncthreads();   // W3L/bL staged

    // ---- persistent state ----
    float m1[16][2];
    #pragma unroll
    for (int i = 0; i < 16; ++i) { m1[i][0] = 0.0f; m1[i][1] = 0.0f; }
    float m2[4][4];
    #pragma unroll
    for (int mt = 0; mt < 4; ++mt)
        #pragma unroll
        for (int rg = 0; rg < 4; ++rg) m2[mt][rg] = 0.0f;
    float m3 = 0.0f, acc3 = 0.0f;

    const unsigned short* fb = W2F + (wv * 24) * 512 + lane * 8;
    const int keyB   = (lane & 7) << 4;
    const int chunkq = lq << 4;
    const int jC     = wv * 16 + l15;
    const int keyC2  = ((jC >> 2) & 7) << 3;

    #pragma unroll 1
    for (int stp = 0; stp < NSTEP; ++stp) {
        // ========== A: layer-1 LIF + bf16 spikes -> LDS ==========
        {
            float c1v[16][2];
            #pragma unroll
            for (int s = 0; s < 2; ++s)
                #pragma unroll
                for (int q = 0; q < 4; ++q) {
                    float4 v = *(const float4*)&myc[((s * 4 + q) ^ tk) * 4];
                    c1v[q * 4 + 0][s] = v.x;
                    c1v[q * 4 + 1][s] = v.y;
                    c1v[q * 4 + 2][s] = v.z;
                    c1v[q * 4 + 3][s] = v.w;
                }
            unsigned int dwa[2][8];
            #pragma unroll
            for (int i = 0; i < 16; ++i) {
                #pragma unroll
                for (int s = 0; s < 2; ++s) {
                    float m = m1[i][s];
                    float r = (m > 1.0f) ? 1.0f : 0.0f;
                    m = __fsub_rn(__fadd_rn(__fmul_rn(0.9f, m), c1v[i][s]), r);
                    m1[i][s] = m;
                    unsigned int bits = (m > 1.0f) ? 0x3F80u : 0u;
                    if (i & 1) dwa[s][i >> 1] |= bits << 16;
                    else       dwa[s][i >> 1]  = bits;
                }
            }
            #pragma unroll
            for (int s = 0; s < 2; ++s) {
                const int row = s0a + s;
                const int key = row & 7;
                char* rp = s1bf + row * 512;
                uint4 lo = make_uint4(dwa[s][0], dwa[s][1], dwa[s][2], dwa[s][3]);
                uint4 hi = make_uint4(dwa[s][4], dwa[s][5], dwa[s][6], dwa[s][7]);
                *(uint4*)(rp + (((2 * nt + 0) ^ key) << 4)) = lo;
                *(uint4*)(rp + (((2 * nt + 1) ^ key) << 4)) = hi;
            }
        }
        __syncthreads();   // bar1: s1 ready

        // ========== B: cur2 = s1 @ W2.T via MFMA (2-deep B prefetch) ========
        f32x4 acc[4];
        {
            const f32x4 z = {0.0f, 0.0f, 0.0f, 0.0f};
            acc[0] = z; acc[1] = z; acc[2] = z; acc[3] = z;
        }
        bf16x8 B2c = *(const bf16x8*)(fb + (16 + 0) * 512);
        bf16x8 B1c = *(const bf16x8*)(fb + (8  + 0) * 512);
        bf16x8 B0c = *(const bf16x8*)(fb + (0  + 0) * 512);
        bf16x8 B2n = *(const bf16x8*)(fb + (16 + 1) * 512);
        bf16x8 B1n = *(const bf16x8*)(fb + (8  + 1) * 512);
        bf16x8 B0n = *(const bf16x8*)(fb + (0  + 1) * 512);
        #pragma unroll
        for (int slab = 0; slab < 8; ++slab) {
            bf16x8 B2f, B1f, B0f;
            if (slab < 6) {
                B2f = *(const bf16x8*)(fb + (16 + slab + 2) * 512);
                B1f = *(const bf16x8*)(fb + (8  + slab + 2) * 512);
                B0f = *(const bf16x8*)(fb + (0  + slab + 2) * 512);
            }
            const int coff = (slab * 64 + chunkq) ^ keyB;
            const bf16x8 A0 = *(const bf16x8*)(s1bf + (l15     ) * 512 + coff);
            const bf16x8 A1 = *(const bf16x8*)(s1bf + (l15 + 16) * 512 + coff);
            const bf16x8 A2 = *(const bf16x8*)(s1bf + (l15 + 32) * 512 + coff);
            const bf16x8 A3 = *(const bf16x8*)(s1bf + (l15 + 48) * 512 + coff);
            acc[0] = __builtin_amdgcn_mfma_f32_16x16x32_bf16(A0, B2c, acc[0], 0, 0, 0);
            acc[1] = __builtin_amdgcn_mfma_f32_16x16x32_bf16(A1, B2c, acc[1], 0, 0, 0);
            acc[2] = __builtin_amdgcn_mfma_f32_16x16x32_bf16(A2, B2c, acc[2], 0, 0, 0);
            acc[3] = __builtin_amdgcn_mfma_f32_16x16x32_bf16(A3, B2c, acc[3], 0, 0, 0);
            acc[0] = __builtin_amdgcn_mfma_f32_16x16x32_bf16(A0, B1c, acc[0], 0, 0, 0);
            acc[1] = __builtin_amdgcn_mfma_f32_16x16x32_bf16(A1, B1c, acc[1], 0, 0, 0);
            acc[2] = __builtin_amdgcn_mfma_f32_16x16x32_bf16(A2, B1c, acc[2], 0, 0, 0);
            acc[3] = __builtin_amdgcn_mfma_f32_16x16x32_bf16(A3, B1c, acc[3], 0, 0, 0);
            acc[0] = __builtin_amdgcn_mfma_f32_16x16x32_bf16(A0, B0c, acc[0], 0, 0, 0);
            acc[1] = __builtin_amdgcn_mfma_f32_16x16x32_bf16(A1, B0c, acc[1], 0, 0, 0);
            acc[2] = __builtin_amdgcn_mfma_f32_16x16x32_bf16(A2, B0c, acc[2], 0, 0, 0);
            acc[3] = __builtin_amdgcn_mfma_f32_16x16x32_bf16(A3, B0c, acc[3], 0, 0, 0);
            if (slab < 7) { B2c = B2n; B1c = B1n; B0c = B0n; }
            if (slab < 6) { B2n = B2f; B1n = B1f; B0n = B0f; }
        }

        // ========== C: layer-2 LIF + u8 spikes -> LDS ==========
        {
            const float bj = bL[jC];
            #pragma unroll
            for (int mt = 0; mt < 4; ++mt) {
                unsigned int pk = 0;
                #pragma unroll
                for (int rg = 0; rg < 4; ++rg) {
                    float c2 = __fadd_rn(acc[mt][rg], bj);
                    float m = m2[mt][rg];
                    float r = (m > 1.0f) ? 1.0f : 0.0f;
                    m = __fsub_rn(__fadd_rn(__fmul_rn(0.9f, m), c2), r);
                    m2[mt][rg] = m;
                    if (m > 1.0f) pk |= 1u << (8 * rg);
                }
                const int smp0 = mt * 16 + lq * 4;
                *(unsigned int*)&s2Lb[jC * 72 + (smp0 ^ keyC2)] = pk;
            }
        }
        __syncthreads();   // bar2: s2 ready

        // ========== D: layer-3 partial dots ==========
        if (t < 256) {
            const int sl = t & 63;
            const int jr = t >> 6;
            float part[5] = {0.0f, 0.0f, 0.0f, 0.0f, 0.0f};
            #pragma unroll 8
            for (int jj = 0; jj < 32; ++jj) {
                const int j = jr * 32 + jj;
                const float s2v =
                    (float)s2Lb[j * 72 + (sl ^ (((j >> 2) & 7) << 3))];
                const float4 w3a = *(const float4*)&W3L[j * 8];
                const float  w3e = W3L[j * 8 + 4];
                part[0] = fmaf(w3a.x, s2v, part[0]);
                part[1] = fmaf(w3a.y, s2v, part[1]);
                part[2] = fmaf(w3a.z, s2v, part[2]);
                part[3] = fmaf(w3a.w, s2v, part[3]);
                part[4] = fmaf(w3e,   s2v, part[4]);
            }
            #pragma unroll
            for (int o = 0; o < 5; ++o)
                pL[(o * 4 + jr) * 64 + sl] = part[o];
        }
        __syncthreads();   // bar3: partials ready

        // ========== E: layer-3 LIF + spike count ==========
        if (t < 320) {
            const int o  = t >> 6;
            const int sl = t & 63;
            float c3 = pL[(o * 4 + 0) * 64 + sl];
            c3 += pL[(o * 4 + 1) * 64 + sl];
            c3 += pL[(o * 4 + 2) * 64 + sl];
            c3 += pL[(o * 4 + 3) * 64 + sl];
            c3 = __fadd_rn(c3, bL[128 + o]);
            float m = m3;
            float r = (m > 1.0f) ? 1.0f : 0.0f;
            m = __fsub_rn(__fadd_rn(__fmul_rn(0.9f, m), c3), r);
            m3 = m;
            if (m > 1.0f) acc3 += 1.0f;
        }
    }

    if (t < 320) {
        out[(sBase + (t & 63)) * 5 + (t >> 6)] = acc3;
    }
}

// ---------------------------------------------------------------------------
// snn_main_fused: EXACT R10 kernel — fallback when ws_size cannot hold cur1G.
// ---------------------------------------------------------------------------
extern "C" __global__ void __launch_bounds__(512, 2) snn_main_fused(
    const float* __restrict__ x,
    const float* __restrict__ b1,
    const float* __restrict__ b2g,
    const float* __restrict__ W3,
    const float* __restrict__ b3,
    const float* __restrict__ W1T,
    const unsigned short* __restrict__ W2F,
    float* __restrict__ out)
{
    __shared__ __align__(16) char ldsraw[68000];
    char* s1bf = ldsraw;
    unsigned char* s2Lb = (unsigned char*)(ldsraw + 32768);
    float* W3L = (float*)(ldsraw + 41984);
    float* pL  = (float*)(ldsraw + 46080);
    float* bL  = (float*)(ldsraw + 51200);
    float* xT  = (float*)(ldsraw);

    const int t    = threadIdx.x;
    const int nt   = t & 15;
    const int st   = t >> 4;
    const int s0a  = st * 2;
    const int n0   = nt * 16;
    const int lane = t & 63;
    const int wv   = t >> 6;
    const int l15  = lane & 15;
    const int lq   = lane >> 4;
    const int sBase = blockIdx.x * 64;

    for (int i = t; i < 64 * 250; i += 512) {
        int sl = i / 250;
        int kl = i - sl * 250;
        xT[kl * 68 + sl] = x[(sBase + sl) * 250 + kl];
    }
    __syncthreads();

    float cur1[16][2];
    #pragma unroll
    for (int i = 0; i < 16; ++i) { cur1[i][0] = 0.0f; cur1[i][1] = 0.0f; }

    #pragma unroll 5
    for (int k = 0; k < 250; ++k) {
        const float2 xp = *(const float2*)&xT[k * 68 + s0a];
        const float x0 = xp.x;
        const float x1 = xp.y;
        float w[16];
        *(float4*)&w[0]  = *(const float4*)&W1T[k * 256 + n0];
        *(float4*)&w[4]  = *(const float4*)&W1T[k * 256 + n0 + 4];
        *(float4*)&w[8]  = *(const float4*)&W1T[k * 256 + n0 + 8];
        *(float4*)&w[12] = *(const float4*)&W1T[k * 256 + n0 + 12];
        #pragma unroll
        for (int i = 0; i < 16; ++i) {
            cur1[i][0] = fmaf(w[i], x0, cur1[i][0]);
            cur1[i][1] = fmaf(w[i], x1, cur1[i][1]);
        }
    }
    {
        float bb[16];
        *(float4*)&bb[0]  = *(const float4*)&b1[n0];
        *(float4*)&bb[4]  = *(const float4*)&b1[n0 + 4];
        *(float4*)&bb[8]  = *(const float4*)&b1[n0 + 8];
        *(float4*)&bb[12] = *(const float4*)&b1[n0 + 12];
        #pragma unroll
        for (int i = 0; i < 16; ++i) {
            cur1[i][0] = __fadd_rn(cur1[i][0], bb[i]);
            cur1[i][1] = __fadd_rn(cur1[i][1], bb[i]);
        }
    }
    __syncthreads();

    for (int idx = t; idx < 640; idx += 512) {
        int o = idx >> 7;
        int j = idx & 127;
        W3L[j * 8 + o] = W3[idx];
    }
    if (t < 128) bL[t] = b2g[t];
    if (t < 5)   bL[128 + t] = b3[t];
    __syncthreads();

    float m1[16][2];
    #pragma unroll
    for (int i = 0; i < 16; ++i) { m1[i][0] = 0.0f; m1[i][1] = 0.0f; }
    float m2[4][4];
    #pragma unroll
    for (int mt = 0; mt < 4; ++mt)
        #pragma unroll
        for (int rg = 0; rg < 4; ++rg) m2[mt][rg] = 0.0f;
    float m3 = 0.0f, acc3 = 0.0f;

    const unsigned short* fb = W2F + (wv * 24) * 512 + lane * 8;
    const int keyB   = (lane & 7) << 4;
    const int chunkq = lq << 4;
    const int jC     = wv * 16 + l15;
    const int keyC2  = ((jC >> 2) & 7) << 3;

    #pragma unroll 1
    for (int stp = 0; stp < NSTEP; ++stp) {
        {
            unsigned int dwa[2][8];
            #pragma unroll
            for (int i = 0; i < 16; ++i) {
                #pragma unroll
                for (int s = 0; s < 2; ++s) {
                    float m = m1[i][s];
                    float r = (m > 1.0f) ? 1.0f : 0.0f;
                    m = __fsub_rn(__fadd_rn(__fmul_rn(0.9f, m), cur1[i][s]), r);
                    m1[i][s] = m;
                    unsigned int bits = (m > 1.0f) ? 0x3F80u : 0u;
                    if (i & 1) dwa[s][i >> 1] |= bits << 16;
                    else       dwa[s][i >> 1]  = bits;
                }
            }
            #pragma unroll
            for (int s = 0; s < 2; ++s) {
                const int row = s0a + s;
                const int key = row & 7;
                char* rp = s1bf + row * 512;
                uint4 lo = make_uint4(dwa[s][0], dwa[s][1], dwa[s][2], dwa[s][3]);
                uint4 hi = make_uint4(dwa[s][4], dwa[s][5], dwa[s][6], dwa[s][7]);
                *(uint4*)(rp + (((2 * nt + 0) ^ key) << 4)) = lo;
                *(uint4*)(rp + (((2 * nt + 1) ^ key) << 4)) = hi;
            }
        }
        __syncthreads();

        f32x4 acc[4];
        {
            const f32x4 z = {0.0f, 0.0f, 0.0f, 0.0f};
            acc[0] = z; acc[1] = z; acc[2] = z; acc[3] = z;
        }
        #pragma unroll
        for (int slab = 0; slab < 8; ++slab) {
            const bf16x8 B2 = *(const bf16x8*)(fb + (16 + slab) * 512);
            const bf16x8 B1 = *(const bf16x8*)(fb + (8  + slab) * 512);
            const bf16x8 B0 = *(const bf16x8*)(fb + (0  + slab) * 512);
            const int coff = (slab * 64 + chunkq) ^ keyB;
            const bf16x8 A0 = *(const bf16x8*)(s1bf + (l15     ) * 512 + coff);
            const bf16x8 A1 = *(const bf16x8*)(s1bf + (l15 + 16) * 512 + coff);
            const bf16x8 A2 = *(const bf16x8*)(s1bf + (l15 + 32) * 512 + coff);
            const bf16x8 A3 = *(const bf16x8*)(s1bf + (l15 + 48) * 512 + coff);
            acc[0] = __builtin_amdgcn_mfma_f32_16x16x32_bf16(A0, B2, acc[0], 0, 0, 0);
            acc[1] = __builtin_amdgcn_mfma_f32_16x16x32_bf16(A1, B2, acc[1], 0, 0, 0);
            acc[2] = __builtin_amdgcn_mfma_f32_16x16x32_bf16(A2, B2, acc[2], 0, 0, 0);
            acc[3] = __builtin_amdgcn_mfma_f32_16x16x32_bf16(A3, B2, acc[3], 0, 0, 0);
            acc[0] = __builtin_amdgcn_mfma_f32_16x16x32_bf16(A0, B1, acc[0], 0, 0, 0);
            acc[1] = __builtin_amdgcn_mfma_f32_16x16x32_bf16(A1, B1, acc[1], 0, 0, 0);
            acc[2] = __builtin_amdgcn_mfma_f32_16x16x32_bf16(A2, B1, acc[2], 0, 0, 0);
            acc[3] = __builtin_amdgcn_mfma_f32_16x16x32_bf16(A3, B1, acc[3], 0, 0, 0);
            acc[0] = __builtin_amdgcn_mfma_f32_16x16x32_bf16(A0, B0, acc[0], 0, 0, 0);
            acc[1] = __builtin_amdgcn_mfma_f32_16x16x32_bf16(A1, B0, acc[1], 0, 0, 0);
            acc[2] = __builtin_amdgcn_mfma_f32_16x16x32_bf16(A2, B0, acc[2], 0, 0, 0);
            acc[3] = __builtin_amdgcn_mfma_f32_16x16x32_bf16(A3, B0, acc[3], 0, 0, 0);
        }

        {
            const float bj = bL[jC];
            #pragma unroll
            for (int mt = 0; mt < 4; ++mt) {
                unsigned int pk = 0;
                #pragma unroll
                for (int rg = 0; rg < 4; ++rg) {
                    float c2 = __fadd_rn(acc[mt][rg], bj);
                    float m = m2[mt][rg];
                    float r = (m > 1.0f) ? 1.0f : 0.0f;
                    m = __fsub_rn(__fadd_rn(__fmul_rn(0.9f, m), c2), r);
                    m2[mt][rg] = m;
                    if (m > 1.0f) pk |= 1u << (8 * rg);
                }
                const int smp0 = mt * 16 + lq * 4;
                *(unsigned int*)&s2Lb[jC * 72 + (smp0 ^ keyC2)] = pk;
            }
        }
        __syncthreads();

        if (t < 256) {
            const int sl = t & 63;
            const int jr = t >> 6;
            float part[5] = {0.0f, 0.0f, 0.0f, 0.0f, 0.0f};
            #pragma unroll 8
            for (int jj = 0; jj < 32; ++jj) {
                const int j = jr * 32 + jj;
                const float s2v =
                    (float)s2Lb[j * 72 + (sl ^ (((j >> 2) & 7) << 3))];
                const float4 w3a = *(const float4*)&W3L[j * 8];
                const float  w3e = W3L[j * 8 + 4];
                part[0] = fmaf(w3a.x, s2v, part[0]);
                part[1] = fmaf(w3a.y, s2v, part[1]);
                part[2] = fmaf(w3a.z, s2v, part[2]);
                part[3] = fmaf(w3a.w, s2v, part[3]);
                part[4] = fmaf(w3e,   s2v, part[4]);
            }
            #pragma unroll
            for (int o = 0; o < 5; ++o)
                pL[(o * 4 + jr) * 64 + sl] = part[o];
        }
        __syncthreads();

        if (t < 320) {
            const int o  = t >> 6;
            const int sl = t & 63;
            float c3 = pL[(o * 4 + 0) * 64 + sl];
            c3 += pL[(o * 4 + 1) * 64 + sl];
            c3 += pL[(o * 4 + 2) * 64 + sl];
            c3 += pL[(o * 4 + 3) * 64 + sl];
            c3 = __fadd_rn(c3, bL[128 + o]);
            float m = m3;
            float r = (m > 1.0f) ? 1.0f : 0.0f;
            m = __fsub_rn(__fadd_rn(__fmul_rn(0.9f, m), c3), r);
            m3 = m;
            if (m > 1.0f) acc3 += 1.0f;
        }
    }

    if (t < 320) {
        out[(sBase + (t & 63)) * 5 + (t >> 6)] = acc3;
    }
}

extern "C" void kernel_launch(void* const* d_in, const int* in_sizes, int n_in,
                              void* d_out, int out_size, void* d_ws, size_t ws_size,
                              hipStream_t stream) {
    const float* x  = (const float*)d_in[0];
    const float* W1 = (const float*)d_in[1];
    const float* b1 = (const float*)d_in[2];
    const float* W2 = (const float*)d_in[3];
    const float* b2 = (const float*)d_in[4];
    const float* W3 = (const float*)d_in[5];
    const float* b3 = (const float*)d_in[6];
    float* out = (float*)d_out;

    float* W1T = (float*)d_ws;                                     // 256000 B
    unsigned short* W2F = (unsigned short*)((char*)d_ws + 262144); // 196608 B

    const int B = in_sizes[0] / 250;      // 131072
    const size_t curBytes = (size_t)B * 256 * sizeof(float);       // 134.2 MB
    const size_t curOff   = 262144 + 196608;                       // 458752

    snn_prep <<<64, 256, 0, stream>>>(W1, W1T);
    snn_prep2<<<48, 256, 0, stream>>>(W2, W2F);

    if (ws_size >= curOff + curBytes) {
        float* curG = (float*)((char*)d_ws + curOff);
        snn_cur1<<<B / 32, 256, 0, stream>>>(x, b1, W1T, curG);
        snn_main_split<<<B / 64, 512, 0, stream>>>(curG, b2, W3, b3, W2F, out);
    } else {
        snn_main_fused<<<B / 64, 512, 0, stream>>>(x, b1, b2, W3, b3, W1T, W2F,
                                                   out);
    }
}